// Round 5
// baseline (182.971 us; speedup 1.0000x reference)
//
#include <hip/hip_runtime.h>

// Conv2d 3x3, cin=4, cout=4, pad=1, stride=1 on [4,4096,4096] fp32.
//
// Round-5 = round-4 with the nontemporal-store type fixed (clang ext_vector
// instead of HIP float4 class). Geometry: thread = 4px x 4rows x 4cout = 64
// acc; block = 1024px x 4 rows; grid = 4096, XCD-bijective swizzle. Explicit
// register double-buffering at the cin-plane level: all 18 loads of plane
// ci+1 issued before the 576 FMAs of plane ci -> load->use distance ~1152
// cycles/wave, 18 loads in flight/wave.

#define IW 4096
#define IH 4096
constexpr long long HWsz = (long long)IH * IW;

typedef float v4f __attribute__((ext_vector_type(4)));

__device__ __forceinline__ void load_plane_rows(float v[6][6],
                                                const float* __restrict__ xin,
                                                int ci, int y0, int x0) {
    const float* plane = xin + (long long)ci * HWsz;
    #pragma unroll
    for (int dy = 0; dy < 6; ++dy) {
        const int yy = y0 + dy - 1;
        if (yy >= 0 && yy < IH) {                 // wave-uniform branch
            const float* rowp = plane + (long long)yy * IW;
            const v4f a = *reinterpret_cast<const v4f*>(rowp + x0);
            v[dy][1] = a.x; v[dy][2] = a.y; v[dy][3] = a.z; v[dy][4] = a.w;
            v[dy][0] = (x0 > 0)      ? rowp[x0 - 1] : 0.f;   // L1-hit halo
            v[dy][5] = (x0 + 4 < IW) ? rowp[x0 + 4] : 0.f;   // L1-hit halo
        } else {
            #pragma unroll
            for (int t = 0; t < 6; ++t) v[dy][t] = 0.f;
        }
    }
}

__device__ __forceinline__ void fma_plane(float acc[4][4][4],
                                          const float v[6][6],
                                          const float* __restrict__ wt, int ci) {
    #pragma unroll
    for (int dy = 0; dy < 6; ++dy) {              // input row index (y0+dy-1)
        #pragma unroll
        for (int r = 0; r < 3; ++r) {             // kernel tap row
            const int yo = dy - r;                // output row offset
            if (yo >= 0 && yo < 4) {
                #pragma unroll
                for (int co = 0; co < 4; ++co) {
                    #pragma unroll
                    for (int kx = 0; kx < 3; ++kx) {
                        const float w = wt[((co * 4 + ci) * 3 + r) * 3 + kx];
                        #pragma unroll
                        for (int p = 0; p < 4; ++p)
                            acc[yo][co][p] = fmaf(w, v[dy][p + kx], acc[yo][co][p]);
                    }
                }
            }
        }
    }
}

__global__ __launch_bounds__(256) void conv3x3_kernel(
    const float* __restrict__ xin,   // [4][4096][4096]
    const float* __restrict__ wt,    // [4][4][3][3]
    float* __restrict__ out)         // [4][4096][4096]
{
    const int nwg = 4096;
    const int cpx = nwg >> 3;                     // XCD-bijective swizzle
    const int bid = blockIdx.x;
    const int swz = (bid & 7) * cpx + (bid >> 3);

    const int rowblk = swz >> 2;                  // [0, 1024)
    const int xblk   = swz & 3;
    const int y0     = rowblk << 2;               // 4 output rows
    const int x0     = (xblk * 256 + (int)threadIdx.x) * 4;  // 16B aligned

    float acc[4][4][4];                           // [orow][cout][px]
    #pragma unroll
    for (int o = 0; o < 4; ++o)
        #pragma unroll
        for (int co = 0; co < 4; ++co)
            #pragma unroll
            for (int p = 0; p < 4; ++p) acc[o][co][p] = 0.f;

    float bufA[6][6], bufB[6][6];                 // double buffer (static idx)

    load_plane_rows(bufA, xin, 0, y0, x0);        // prologue: plane 0

    // ci = 0: prefetch plane 1 into B, compute A
    load_plane_rows(bufB, xin, 1, y0, x0);
    fma_plane(acc, bufA, wt, 0);
    // ci = 1: prefetch plane 2 into A, compute B
    load_plane_rows(bufA, xin, 2, y0, x0);
    fma_plane(acc, bufB, wt, 1);
    // ci = 2: prefetch plane 3 into B, compute A
    load_plane_rows(bufB, xin, 3, y0, x0);
    fma_plane(acc, bufA, wt, 2);
    // ci = 3: compute B
    fma_plane(acc, bufB, wt, 3);

    #pragma unroll
    for (int o = 0; o < 4; ++o) {
        const long long obase = (long long)(y0 + o) * IW + x0;
        #pragma unroll
        for (int co = 0; co < 4; ++co) {
            v4f ov;
            ov.x = acc[o][co][0]; ov.y = acc[o][co][1];
            ov.z = acc[o][co][2]; ov.w = acc[o][co][3];
            __builtin_nontemporal_store(ov,
                reinterpret_cast<v4f*>(out + co * HWsz + obase));
        }
    }
}

extern "C" void kernel_launch(void* const* d_in, const int* in_sizes, int n_in,
                              void* d_out, int out_size, void* d_ws, size_t ws_size,
                              hipStream_t stream) {
    const float* xin = (const float*)d_in[0];
    const float* wt  = (const float*)d_in[1];
    float* out       = (float*)d_out;

    dim3 grid(4096), block(256);
    hipLaunchKernelGGL(conv3x3_kernel, grid, block, 0, stream, xin, wt, out);
}